// Round 19
// baseline (454.433 us; speedup 1.0000x reference)
//
#include <hip/hip_runtime.h>
#include <math.h>

typedef unsigned long long u64;
typedef float vf4 __attribute__((ext_vector_type(4)));

constexpr int T_TOTAL = 16777216;          // 2^24
constexpr int TPB     = 256;               // 4 waves per block
constexpr int SEG_B   = 8192;              // elements per block
constexpr int NBLK    = T_TOTAL / SEG_B;   // 2048 blocks (8/CU)
constexpr int SEG_W   = SEG_B / 4;         // 2048 elements per wave
constexpr int ITW     = SEG_W / 128;       // 16 iterations per wave
constexpr float THRESHOLD = 0.5f;

// Phase-A step: ballots + intra-wave prefix base into LDS (math validated r10/r17)
#define MPROC(it, a, c)                                                       \
    {                                                                         \
        u64 pe_ = __ballot((a).x > (c).x);                                    \
        u64 ne_ = __ballot((c).x > (a).x);                                    \
        u64 po_ = __ballot((a).y > (c).y);                                    \
        u64 no_ = __ballot((c).y > (a).y);                                    \
        if (lane == 0) ibase[wid][it] = ssum;                                 \
        u64 v = pe_;                                                          \
        v = (lane == 1) ? ne_ : v;                                            \
        v = (lane == 2) ? po_ : v;                                            \
        v = (lane == 3) ? no_ : v;                                            \
        if (lane < 4) ball[wid][it][lane] = v;                                \
        ssum += __popcll(pe_) - __popcll(ne_) + __popcll(po_) - __popcll(no_);\
    }

// Phase-C step: iteration-independent count from LDS ballots (validated r17)
#define PROCC(it, uv, ev)                                                     \
    {                                                                         \
        u64 w0 = ball[wid][it][0], w1 = ball[wid][it][1];                     \
        u64 w2 = ball[wid][it][2], w3 = ball[wid][it][3];                     \
        const int bp = pre + ibase[wid][it];                                  \
        const int de = __popcll(w0 & le) - __popcll(w1 & le);                 \
        const int pe2 = bp + de + __popcll(w2 & lt) - __popcll(w3 & lt);      \
        const int po2 = bp + de + __popcll(w2 & le) - __popcll(w3 & le);      \
        const int a0 = pe2 > 0, a1 = po2 > 0;                                 \
        cact += a0 + a1;                                                      \
        if (a0 && fabsf((ev)[0] - (uv)[0]) > THRESHOLD) cover++;              \
        if (a1 && fabsf((ev)[2] - (uv)[2]) > THRESHOLD) cover++;              \
    }

// Single-pass: ticket-ordered blocks, decoupled lookback for the global
// prefix, fused count, done-counter final. flags[vb] = (flag<<32)|value,
// flag: 0=invalid 1=aggregate 2=inclusive. Ticket order guarantees every
// lower ticket is held by an earlier-resident block -> no circular wait.
__global__ void __launch_bounds__(TPB)
k_fused(const int2* __restrict__ on2, const int2* __restrict__ off2,
        const vf4* __restrict__ u4, const vf4* __restrict__ e4,
        unsigned* __restrict__ ticket, unsigned* __restrict__ done,
        int* __restrict__ counters, u64* __restrict__ flags,
        float* __restrict__ out) {
    __shared__ u64 ball[4][ITW][4];            // 2 KB
    __shared__ int ibase[4][ITW];              // 256 B
    __shared__ int wsum[4], sc[4], sa[4];
    __shared__ int vb_s, excl_s;
    const int lane = threadIdx.x & 63;
    const int wid  = threadIdx.x >> 6;

    if (threadIdx.x == 0) vb_s = (int)atomicAdd(ticket, 1u);
    __syncthreads();
    const int vb   = vb_s;
    const int base = (vb * 4 + wid) * (SEG_W / 2);   // int2 == float4 index
    const u64 le = (~0ull) >> (63 - lane);
    const u64 lt = le >> 1;

    // ---- Phase A: on/off -> LDS ballots + wave sum ----
    int ssum = 0;
    #pragma unroll
    for (int g = 0; g < ITW / 4; ++g) {
        const int i0 = base + g * 256 + lane;
        int2 a0 = on2[i0];        int2 a1 = on2[i0 + 64];
        int2 a2 = on2[i0 + 128];  int2 a3 = on2[i0 + 192];
        int2 c0 = off2[i0];       int2 c1 = off2[i0 + 64];
        int2 c2 = off2[i0 + 128]; int2 c3 = off2[i0 + 192];
        MPROC(4 * g + 0, a0, c0);
        MPROC(4 * g + 1, a1, c1);
        MPROC(4 * g + 2, a2, c2);
        MPROC(4 * g + 3, a3, c3);
    }
    if (lane == 0) wsum[wid] = ssum;
    __syncthreads();

    // ---- Lookback (wave 0) ----
    if (wid == 0) {
        const int agg = wsum[0] + wsum[1] + wsum[2] + wsum[3];
        if (lane == 0) {
            u64 f = ((u64)(vb == 0 ? 2u : 1u) << 32) | (unsigned)agg;
            __hip_atomic_store(&flags[vb], f, __ATOMIC_RELEASE,
                               __HIP_MEMORY_SCOPE_AGENT);
        }
        int excl = 0;
        if (vb > 0) {
            int look = vb - 1;
            while (true) {
                const int idx = look - lane;
                u64 f;
                do {
                    f = (idx >= 0)
                      ? __hip_atomic_load(&flags[idx], __ATOMIC_ACQUIRE,
                                          __HIP_MEMORY_SCOPE_AGENT)
                      : ((u64)2u << 32);
                } while ((unsigned)(f >> 32) == 0u);
                const u64 binc = __ballot((unsigned)(f >> 32) == 2u);
                const int v = (int)(unsigned)(f & 0xffffffffu);
                if (binc) {
                    const int L = (int)__ffsll((long long)binc) - 1;
                    int contrib = (lane <= L) ? v : 0;   // aggs < L, inclusive at L
                    #pragma unroll
                    for (int d = 32; d > 0; d >>= 1) contrib += __shfl_xor(contrib, d);
                    excl += contrib;
                    break;
                } else {                                  // 64 aggregates: step back
                    int contrib = v;
                    #pragma unroll
                    for (int d = 32; d > 0; d >>= 1) contrib += __shfl_xor(contrib, d);
                    excl += contrib;
                    look -= 64;
                }
            }
            if (lane == 0) {
                u64 f = ((u64)2u << 32) | (unsigned)(excl + agg);
                __hip_atomic_store(&flags[vb], f, __ATOMIC_RELEASE,
                                   __HIP_MEMORY_SCOPE_AGENT);
            }
        }
        if (lane == 0) excl_s = excl;
    }
    __syncthreads();

    // ---- Phase C: clean u/e-only nt streaming + count ----
    int pre = excl_s;
    #pragma unroll
    for (int w = 0; w < 3; w++) if (w < wid) pre += wsum[w];

    int cover = 0, cact = 0;
    #pragma unroll
    for (int g = 0; g < ITW / 4; ++g) {
        const int i0 = base + g * 256 + lane;
        vf4 u0 = __builtin_nontemporal_load(u4 + i0);
        vf4 u1 = __builtin_nontemporal_load(u4 + i0 + 64);
        vf4 u2 = __builtin_nontemporal_load(u4 + i0 + 128);
        vf4 u3 = __builtin_nontemporal_load(u4 + i0 + 192);
        vf4 e0 = __builtin_nontemporal_load(e4 + i0);
        vf4 e1 = __builtin_nontemporal_load(e4 + i0 + 64);
        vf4 e2 = __builtin_nontemporal_load(e4 + i0 + 128);
        vf4 e3 = __builtin_nontemporal_load(e4 + i0 + 192);
        PROCC(4 * g + 0, u0, e0);
        PROCC(4 * g + 1, u1, e1);
        PROCC(4 * g + 2, u2, e2);
        PROCC(4 * g + 3, u3, e3);
    }

    // ---- Phase D: reduce, accumulate, last block writes quotient ----
    #pragma unroll
    for (int d = 32; d > 0; d >>= 1) {
        cover += __shfl_xor(cover, d);
        cact  += __shfl_xor(cact, d);
    }
    if (lane == 0) { sc[wid] = cover; sa[wid] = cact; }
    __syncthreads();
    if (threadIdx.x == 0) {
        atomicAdd(&counters[0], sc[0] + sc[1] + sc[2] + sc[3]);
        atomicAdd(&counters[1], sa[0] + sa[1] + sa[2] + sa[3]);
        __threadfence();
        const unsigned old = atomicAdd(done, 1u);
        if (old == (unsigned)(NBLK - 1)) {
            __threadfence();
            const int c = __hip_atomic_load(&counters[0], __ATOMIC_ACQUIRE,
                                            __HIP_MEMORY_SCOPE_AGENT);
            const int a = __hip_atomic_load(&counters[1], __ATOMIC_ACQUIRE,
                                            __HIP_MEMORY_SCOPE_AGENT);
            out[0] = (float)c / (float)a;
        }
    }
}

extern "C" void kernel_launch(void* const* d_in, const int* in_sizes, int n_in,
                              void* d_out, int out_size, void* d_ws, size_t ws_size,
                              hipStream_t stream) {
    const int2* on2  = (const int2*)d_in[2];
    const int2* off2 = (const int2*)d_in[3];
    const vf4*  u4   = (const vf4*)d_in[0];
    const vf4*  e4   = (const vf4*)d_in[1];

    unsigned* ticket   = (unsigned*)d_ws;                  // +0
    unsigned* done     = (unsigned*)d_ws + 1;              // +4
    int*      counters = (int*)d_ws + 2;                   // +8: 2 ints
    u64*      flags    = (u64*)((char*)d_ws + 64);         // NBLK u64 (16 KB)

    hipMemsetAsync(d_ws, 0, 64 + NBLK * sizeof(u64), stream);
    k_fused<<<NBLK, TPB, 0, stream>>>(on2, off2, u4, e4,
                                      ticket, done, counters, flags,
                                      (float*)d_out);
}

// Round 20
// 82.584 us; speedup vs baseline: 5.5027x; 5.5027x over previous
//
#include <hip/hip_runtime.h>
#include <math.h>

typedef unsigned long long u64;
typedef float vf4 __attribute__((ext_vector_type(4)));

constexpr int T_TOTAL = 16777216;          // 2^24
constexpr int TPB     = 256;               // 4 waves per block
constexpr int SEG     = 2048;              // elements per wave segment
constexpr int NSEG    = T_TOTAL / SEG;     // 8192 segments
constexpr int NBLK    = NSEG / 4;          // 2048 blocks
constexpr int ITERS   = SEG / 128;         // 16 iterations per wave
constexpr float THRESHOLD = 0.5f;

// ---------------- pass 1: masks + intra-segment prefix bases ----------------
// Reads ONLY on/off (128 MB, L3-resident across replays since u/e bypass L3
// via nt). Emits per-(seg,iter): 4 ballot words + prefix base + segment sums.
// Math validated r10/r17 (absmax 0.0).
#define MPROC(a, c)                                                           \
    {                                                                         \
        u64 pe_ = __ballot((a).x > (c).x);                                    \
        u64 ne_ = __ballot((c).x > (a).x);                                    \
        u64 po_ = __ballot((a).y > (c).y);                                    \
        u64 no_ = __ballot((c).y > (a).y);                                    \
        if (lane == 0) ibases[rec] = ssum;                                    \
        u64 v = pe_;                                                          \
        v = (lane == 1) ? ne_ : v;                                            \
        v = (lane == 2) ? po_ : v;                                            \
        v = (lane == 3) ? no_ : v;                                            \
        if (lane < 4) ballots[(size_t)rec * 4 + lane] = v;                    \
        ssum += __popcll(pe_) - __popcll(ne_) + __popcll(po_) - __popcll(no_);\
        rec++;                                                                \
    }

__global__ void __launch_bounds__(TPB)
k_masks(const int2* __restrict__ on2, const int2* __restrict__ off2,
        u64* __restrict__ ballots, int* __restrict__ ibases,
        int* __restrict__ segsums) {
    const int lane = threadIdx.x & 63;
    const int wid  = threadIdx.x >> 6;
    const int seg  = blockIdx.x * 4 + wid;
    const int base = seg * (SEG / 2);          // int2 index
    int ssum = 0;
    int rec  = seg * ITERS;
    #pragma unroll
    for (int g = 0; g < ITERS / 4; ++g) {
        const int i0 = base + g * 256 + lane;
        int2 a0 = on2[i0];        int2 a1 = on2[i0 + 64];
        int2 a2 = on2[i0 + 128];  int2 a3 = on2[i0 + 192];
        int2 c0 = off2[i0];       int2 c1 = off2[i0 + 64];
        int2 c2 = off2[i0 + 128]; int2 c3 = off2[i0 + 192];
        MPROC(a0, c0);
        MPROC(a1, c1);
        MPROC(a2, c2);
        MPROC(a3, c3);
    }
    if (lane == 0) segsums[seg] = ssum;
}

// ---------------- pass 2: scan of segment sums ----------------
__global__ void __launch_bounds__(TPB)
k_scan(int* __restrict__ segsums) {
    __shared__ int wsum[4];
    const int lane = threadIdx.x & 63;
    const int wid  = threadIdx.x >> 6;
    int vals[NSEG / TPB];
    const int base = threadIdx.x * (NSEG / TPB);
    int s = 0;
    #pragma unroll
    for (int i = 0; i < NSEG / TPB; i++) { vals[i] = segsums[base + i]; s += vals[i]; }
    int x = s;
    #pragma unroll
    for (int d = 1; d < 64; d <<= 1) {
        int y = __shfl_up(x, d);
        if (lane >= d) x += y;
    }
    if (lane == 63) wsum[wid] = x;
    __syncthreads();
    int wbase = 0;
    #pragma unroll
    for (int w = 0; w < 3; w++) if (w < wid) wbase += wsum[w];
    int ex = wbase + (x - s);
    #pragma unroll
    for (int i = 0; i < NSEG / TPB; i++) { int v = vals[i]; segsums[base + i] = ex; ex += v; }
}

// Phase-C step: iteration-independent count from L2-hot ballots
#define PROCC(it, uv, ev)                                                     \
    {                                                                         \
        ulonglong2 w01 = mybb[2 * (it)];       /* pos_e, neg_e */             \
        ulonglong2 w23 = mybb[2 * (it) + 1];   /* pos_o, neg_o */             \
        const int bp = sp + myib[it];                                         \
        const int de = __popcll(w01.x & le) - __popcll(w01.y & le);           \
        const int pe2 = bp + de + __popcll(w23.x & lt) - __popcll(w23.y & lt);\
        const int po2 = bp + de + __popcll(w23.x & le) - __popcll(w23.y & le);\
        const int a0 = pe2 > 0, a1 = po2 > 0;                                 \
        cact += a0 + a1;                                                      \
        if (a0 && fabsf((ev)[0] - (uv)[0]) > THRESHOLD) cover++;              \
        if (a1 && fabsf((ev)[2] - (uv)[2]) > THRESHOLD) cover++;              \
    }

// ---------------- pass 3: clean u/e-only nt streaming ----------------
// No __ballot, no serial chain, only two HBM streams (nt) + L2-hot masks.
__global__ void __launch_bounds__(TPB)
k_count2(const vf4* __restrict__ u4, const vf4* __restrict__ e4,
         const ulonglong2* __restrict__ bb, const int* __restrict__ ibases,
         const int* __restrict__ segpre, int2* __restrict__ partials) {
    const int lane = threadIdx.x & 63;
    const int wid  = threadIdx.x >> 6;
    const int seg  = blockIdx.x * 4 + wid;
    const int base = seg * (SEG / 2);          // float4 index
    const u64 le = (~0ull) >> (63 - lane);     // lanes 0..i
    const u64 lt = le >> 1;                    // lanes 0..i-1

    const int sp = segpre[seg];
    const ulonglong2* mybb = bb + (size_t)seg * ITERS * 2;
    const int* myib = ibases + seg * ITERS;

    int cover = 0, cact = 0;
    #pragma unroll
    for (int g = 0; g < ITERS / 4; ++g) {
        const int i0 = base + g * 256 + lane;
        vf4 u0 = __builtin_nontemporal_load(u4 + i0);
        vf4 u1 = __builtin_nontemporal_load(u4 + i0 + 64);
        vf4 u2 = __builtin_nontemporal_load(u4 + i0 + 128);
        vf4 u3 = __builtin_nontemporal_load(u4 + i0 + 192);
        vf4 e0 = __builtin_nontemporal_load(e4 + i0);
        vf4 e1 = __builtin_nontemporal_load(e4 + i0 + 64);
        vf4 e2 = __builtin_nontemporal_load(e4 + i0 + 128);
        vf4 e3 = __builtin_nontemporal_load(e4 + i0 + 192);
        PROCC(4 * g + 0, u0, e0);
        PROCC(4 * g + 1, u1, e1);
        PROCC(4 * g + 2, u2, e2);
        PROCC(4 * g + 3, u3, e3);
    }

    #pragma unroll
    for (int d = 32; d > 0; d >>= 1) {
        cover += __shfl_xor(cover, d);
        cact  += __shfl_xor(cact, d);
    }
    __shared__ int sc[4], sa[4];
    if (lane == 0) { sc[wid] = cover; sa[wid] = cact; }
    __syncthreads();
    if (threadIdx.x == 0)
        partials[blockIdx.x] = make_int2(sc[0] + sc[1] + sc[2] + sc[3],
                                         sa[0] + sa[1] + sa[2] + sa[3]);
}

// ---------------- fallback path (r14 proven, absmax 0.0) ----------------
__global__ void __launch_bounds__(TPB)
k_segsums(const int2* __restrict__ on2, const int2* __restrict__ off2,
          int* __restrict__ segsums) {
    const int lane = threadIdx.x & 63;
    const int wid  = threadIdx.x >> 6;
    const int seg  = blockIdx.x * 4 + wid;
    const int base = seg * (SEG / 2);
    int s = 0;
    #pragma unroll
    for (int g = 0; g < ITERS / 4; ++g) {
        const int i0 = base + g * 256 + lane;
        int2 a0 = on2[i0];        int2 a1 = on2[i0 + 64];
        int2 a2 = on2[i0 + 128];  int2 a3 = on2[i0 + 192];
        int2 c0 = off2[i0];       int2 c1 = off2[i0 + 64];
        int2 c2 = off2[i0 + 128]; int2 c3 = off2[i0 + 192];
        s += (a0.x + a0.y - c0.x - c0.y) + (a1.x + a1.y - c1.x - c1.y)
           + (a2.x + a2.y - c2.x - c2.y) + (a3.x + a3.y - c3.x - c3.y);
    }
    #pragma unroll
    for (int d = 32; d > 0; d >>= 1) s += __shfl_xor(s, d);
    if (lane == 0) segsums[seg] = s;
}

#define PROC(a, c, uv, ev)                                                    \
    {                                                                         \
        u64 be_on  = __ballot((a).x != 0);                                    \
        u64 bo_on  = __ballot((a).y != 0);                                    \
        u64 be_off = __ballot((c).x != 0);                                    \
        u64 bo_off = __ballot((c).y != 0);                                    \
        const int de = __popcll(be_on & le) - __popcll(be_off & le);          \
        const int pe = basep + de + __popcll(bo_on & lt) - __popcll(bo_off & lt); \
        const int po = basep + de + __popcll(bo_on & le) - __popcll(bo_off & le); \
        basep += __popcll(be_on) - __popcll(be_off)                           \
               + __popcll(bo_on) - __popcll(bo_off);                          \
        const int a0 = pe > 0, a1 = po > 0;                                   \
        cact += a0 + a1;                                                      \
        if (a0 && fabsf((ev)[0] - (uv)[0]) > THRESHOLD) cover++;              \
        if (a1 && fabsf((ev)[2] - (uv)[2]) > THRESHOLD) cover++;              \
    }

__global__ void __launch_bounds__(TPB)
k_count(const int2* __restrict__ on2, const int2* __restrict__ off2,
        const vf4* __restrict__ u4, const vf4* __restrict__ e4,
        const int* __restrict__ segpre, int2* __restrict__ partials) {
    const int lane = threadIdx.x & 63;
    const int wid  = threadIdx.x >> 6;
    const int seg  = blockIdx.x * 4 + wid;
    const int base = seg * (SEG / 2);
    const u64 le = (~0ull) >> (63 - lane);
    const u64 lt = le >> 1;
    int basep = segpre[seg];
    int cover = 0, cact = 0;
    #pragma unroll
    for (int g = 0; g < ITERS / 4; ++g) {
        const int i0 = base + g * 256 + lane;
        int2 a0 = on2[i0];        int2 a1 = on2[i0 + 64];
        int2 a2 = on2[i0 + 128];  int2 a3 = on2[i0 + 192];
        int2 c0 = off2[i0];       int2 c1 = off2[i0 + 64];
        int2 c2 = off2[i0 + 128]; int2 c3 = off2[i0 + 192];
        vf4 u0 = __builtin_nontemporal_load(u4 + i0);
        vf4 u1 = __builtin_nontemporal_load(u4 + i0 + 64);
        vf4 u2 = __builtin_nontemporal_load(u4 + i0 + 128);
        vf4 u3 = __builtin_nontemporal_load(u4 + i0 + 192);
        vf4 e0 = __builtin_nontemporal_load(e4 + i0);
        vf4 e1 = __builtin_nontemporal_load(e4 + i0 + 64);
        vf4 e2 = __builtin_nontemporal_load(e4 + i0 + 128);
        vf4 e3 = __builtin_nontemporal_load(e4 + i0 + 192);
        PROC(a0, c0, u0, e0);
        PROC(a1, c1, u1, e1);
        PROC(a2, c2, u2, e2);
        PROC(a3, c3, u3, e3);
    }
    #pragma unroll
    for (int d = 32; d > 0; d >>= 1) {
        cover += __shfl_xor(cover, d);
        cact  += __shfl_xor(cact, d);
    }
    __shared__ int sc[4], sa[4];
    if (lane == 0) { sc[wid] = cover; sa[wid] = cact; }
    __syncthreads();
    if (threadIdx.x == 0)
        partials[blockIdx.x] = make_int2(sc[0] + sc[1] + sc[2] + sc[3],
                                         sa[0] + sa[1] + sa[2] + sa[3]);
}

// ---------------- final reduce ----------------
__global__ void __launch_bounds__(TPB)
k_final(const int2* __restrict__ partials, float* __restrict__ out) {
    const int lane = threadIdx.x & 63;
    const int wid  = threadIdx.x >> 6;
    int c = 0, a = 0;
    for (int i = threadIdx.x; i < NBLK; i += TPB) {
        int2 p = partials[i];
        c += p.x; a += p.y;
    }
    #pragma unroll
    for (int d = 32; d > 0; d >>= 1) {
        c += __shfl_xor(c, d);
        a += __shfl_xor(a, d);
    }
    __shared__ int sc[4], sa[4];
    if (lane == 0) { sc[wid] = c; sa[wid] = a; }
    __syncthreads();
    if (threadIdx.x == 0) {
        float ctot = (float)(sc[0] + sc[1] + sc[2] + sc[3]);
        float atot = (float)(sa[0] + sa[1] + sa[2] + sa[3]);
        out[0] = ctot / atot;
    }
}

extern "C" void kernel_launch(void* const* d_in, const int* in_sizes, int n_in,
                              void* d_out, int out_size, void* d_ws, size_t ws_size,
                              hipStream_t stream) {
    const float* u   = (const float*)d_in[0];
    const float* e   = (const float*)d_in[1];
    const int*   on  = (const int*)d_in[2];
    const int*   off = (const int*)d_in[3];

    int*  segsums  = (int*)d_ws;                          // 32 KB
    int2* partials = (int2*)(segsums + NSEG);             // 16 KB
    int*  ibases   = (int*)((char*)d_ws + 48 * 1024);     // 512 KB
    u64*  ballots  = (u64*)((char*)d_ws + 560 * 1024);    // 4 MB

    const size_t need = 560 * 1024 + (size_t)NSEG * ITERS * 4 * sizeof(u64);

    if (ws_size >= need) {
        k_masks<<<NBLK, TPB, 0, stream>>>((const int2*)on, (const int2*)off,
                                          ballots, ibases, segsums);
        k_scan<<<1, TPB, 0, stream>>>(segsums);
        k_count2<<<NBLK, TPB, 0, stream>>>((const vf4*)u, (const vf4*)e,
                                           (const ulonglong2*)ballots, ibases,
                                           segsums, partials);
    } else {
        k_segsums<<<NBLK, TPB, 0, stream>>>((const int2*)on, (const int2*)off, segsums);
        k_scan<<<1, TPB, 0, stream>>>(segsums);
        k_count<<<NBLK, TPB, 0, stream>>>((const int2*)on, (const int2*)off,
                                          (const vf4*)u, (const vf4*)e,
                                          segsums, partials);
    }
    k_final<<<1, TPB, 0, stream>>>(partials, (float*)d_out);
}